// Round 1
// baseline (6669.550 us; speedup 1.0000x reference)
//
#include <hip/hip_runtime.h>
#include <hip/hip_bf16.h>
#include <math.h>

#define BB 16
#define II 512
#define JJ 2048
#define CT 512
#define CM 80
#define AC 80

#define NEGF (-1000000000.0f)
#define TEMPF 0.0005f
#define BLANKF (-1.0f)

__device__ __forceinline__ float lae(float a, float b) {
  float m = fmaxf(a, b);
  return m + log1pf(expf(-fabsf(a - b)));
}

// ---------------- lens: key_lens[b] = sum(text_mask), query_lens[b] = sum(mel_mask)
__global__ void compute_lens(const int* __restrict__ tmask, const int* __restrict__ mmask,
                             int* __restrict__ lens) {
  __shared__ int sred[256];
  int b = blockIdx.x, tid = threadIdx.x;
  int s = 0;
  for (int i = tid; i < II; i += 256) s += (tmask[b * II + i] > 0);
  sred[tid] = s; __syncthreads();
  for (int st = 128; st > 0; st >>= 1) { if (tid < st) sred[tid] += sred[tid + st]; __syncthreads(); }
  if (tid == 0) lens[b] = sred[0];
  __syncthreads();
  s = 0;
  for (int i = tid; i < JJ; i += 256) s += (mmask[b * JJ + i] > 0);
  sred[tid] = s; __syncthreads();
  for (int st = 128; st > 0; st >>= 1) { if (tid < st) sred[tid] += sred[tid + st]; __syncthreads(); }
  if (tid == 0) lens[BB + b] = sred[0];
}

// ---------------- transpose (B, L, C) -> (B, C, L)
__global__ void transpose_bc(const float* __restrict__ x, float* __restrict__ y, int L, int C) {
  __shared__ float tile[32][33];
  int b = blockIdx.z;
  int l0 = blockIdx.x * 32, c0 = blockIdx.y * 32;
  int tx = threadIdx.x, ty = threadIdx.y;
  for (int r = ty; r < 32; r += 8) {
    int l = l0 + r, c = c0 + tx;
    tile[r][tx] = (l < L && c < C) ? x[((size_t)b * L + l) * C + c] : 0.f;
  }
  __syncthreads();
  for (int r = ty; r < 32; r += 8) {
    int c = c0 + r, l = l0 + tx;
    if (c < C && l < L) y[((size_t)b * C + c) * L + l] = tile[tx][r];
  }
}

// ---------------- conv k=3 SAME + relu: Y[b][o][l] = relu(bias[o] + sum_{c,dt} W[o][c][dt]*X[b][c][l+dt-1])
// tile: 64 o x 128 l, 256 threads, micro 4o x 8l
__global__ __launch_bounds__(256) void conv3_relu(
    const float* __restrict__ X, const float* __restrict__ W,
    const float* __restrict__ bias, float* __restrict__ Y,
    int Cin, int O, int L) {
  __shared__ float xs[16][132];
  __shared__ float wsm[64][49];
  int b = blockIdx.z;
  int l0 = blockIdx.x * 128;
  int o0 = blockIdx.y * 64;
  int tid = threadIdx.x;
  int tx = tid & 15, ty = tid >> 4;
  float acc[4][8] = {};
  const float* Xb = X + (size_t)b * Cin * L;
  for (int c0 = 0; c0 < Cin; c0 += 16) {
    for (int idx = tid; idx < 16 * 130; idx += 256) {
      int cc = idx / 130, ll = idx % 130;
      int l = l0 + ll - 1;
      xs[cc][ll] = (l >= 0 && l < L) ? Xb[(size_t)(c0 + cc) * L + l] : 0.f;
    }
    for (int idx = tid; idx < 64 * 48; idx += 256) {
      int oo = idx / 48, kx = idx % 48;
      int o = o0 + oo;
      wsm[oo][kx] = (o < O) ? W[((size_t)o * Cin + (c0 + (kx / 3))) * 3 + (kx % 3)] : 0.f;
    }
    __syncthreads();
    #pragma unroll 4
    for (int cc = 0; cc < 16; ++cc) {
      float xr[10];
      #pragma unroll
      for (int u = 0; u < 10; ++u) xr[u] = xs[cc][tx * 8 + u];
      #pragma unroll
      for (int a = 0; a < 4; ++a) {
        float w0 = wsm[ty * 4 + a][cc * 3 + 0];
        float w1 = wsm[ty * 4 + a][cc * 3 + 1];
        float w2 = wsm[ty * 4 + a][cc * 3 + 2];
        #pragma unroll
        for (int ii = 0; ii < 8; ++ii)
          acc[a][ii] += w0 * xr[ii] + w1 * xr[ii + 1] + w2 * xr[ii + 2];
      }
    }
    __syncthreads();
  }
  #pragma unroll
  for (int a = 0; a < 4; ++a) {
    int o = o0 + ty * 4 + a;
    if (o < O) {
      float bv = bias[o];
      #pragma unroll
      for (int ii = 0; ii < 8; ++ii) {
        int l = l0 + tx * 8 + ii;
        Y[((size_t)b * O + o) * L + l] = fmaxf(acc[a][ii] + bv, 0.f);
      }
    }
  }
}

// ---------------- pointwise GEMM: Y[b][a][l] = act(bias[a] + sum_k W[a][k]*X[b][k][l]); Aout=80
// optional sq[b][l] = sum_a Y^2
__global__ __launch_bounds__(256) void pw_gemm(
    const float* __restrict__ X, const float* __restrict__ W,
    const float* __restrict__ bias, float* __restrict__ Y,
    float* __restrict__ sq, int K, int L, int relu) {
  __shared__ float xsm[16][65];
  __shared__ float wsm[80][17];
  __shared__ float red[4][64];
  int b = blockIdx.y;
  int l0 = blockIdx.x * 64;
  int tid = threadIdx.x;
  int tx = tid & 63, ty = tid >> 6;
  float acc[20] = {};
  const float* Xb = X + (size_t)b * K * L;
  for (int k0 = 0; k0 < K; k0 += 16) {
    for (int idx = tid; idx < 16 * 64; idx += 256) {
      int kk = idx >> 6, ll = idx & 63;
      xsm[kk][ll] = Xb[(size_t)(k0 + kk) * L + l0 + ll];
    }
    for (int idx = tid; idx < 80 * 16; idx += 256) {
      int aa = idx >> 4, kk = idx & 15;
      wsm[aa][kk] = W[(size_t)aa * K + k0 + kk];
    }
    __syncthreads();
    #pragma unroll 4
    for (int kk = 0; kk < 16; ++kk) {
      float xv = xsm[kk][tx];
      #pragma unroll
      for (int aa = 0; aa < 20; ++aa) acc[aa] += wsm[ty + 4 * aa][kk] * xv;
    }
    __syncthreads();
  }
  float s2 = 0.f;
  #pragma unroll
  for (int aa = 0; aa < 20; ++aa) {
    int a = ty + 4 * aa;
    float v = acc[aa] + bias[a];
    if (relu) v = fmaxf(v, 0.f);
    Y[((size_t)b * 80 + a) * L + l0 + tx] = v;
    s2 += v * v;
  }
  if (sq) {
    red[ty][tx] = s2;
    __syncthreads();
    if (ty == 0) sq[(size_t)b * L + l0 + tx] = red[0][tx] + red[1][tx] + red[2][tx] + red[3][tx];
  }
}

// ---------------- attention: dist logits + log_softmax + prior + mask -> logp; softmax -> soft
// block: (b, 16 j-rows) x full i=512; 256 threads, each 2 i (tid, tid+256)
__global__ __launch_bounds__(256) void attn_logits(
    const float* __restrict__ q, const float* __restrict__ k,
    const float* __restrict__ q2, const float* __restrict__ k2,
    const float* __restrict__ prior, const int* __restrict__ tmask,
    float* __restrict__ soft, float* __restrict__ logp) {
  __shared__ float kS[16][II];
  __shared__ float qS[16][16];
  __shared__ float red[16][257];
  int b = blockIdx.y;
  int j0 = blockIdx.x * 16;
  int tid = threadIdx.x;
  float acc0[16] = {}, acc1[16] = {};
  for (int c0 = 0; c0 < AC; c0 += 16) {
    for (int idx = tid; idx < 16 * II; idx += 256) {
      int cc = idx >> 9, ii = idx & 511;
      kS[cc][ii] = k[((size_t)b * AC + c0 + cc) * II + ii];
    }
    {
      int cc = tid >> 4, jl = tid & 15;
      qS[cc][jl] = q[((size_t)b * AC + c0 + cc) * JJ + j0 + jl];
    }
    __syncthreads();
    #pragma unroll 4
    for (int cc = 0; cc < 16; ++cc) {
      float k0v = kS[cc][tid], k1v = kS[cc][tid + 256];
      #pragma unroll
      for (int jj = 0; jj < 16; ++jj) {
        float qv = qS[cc][jj];
        acc0[jj] += qv * k0v;
        acc1[jj] += qv * k1v;
      }
    }
    __syncthreads();
  }
  float k2a = k2[(size_t)b * II + tid];
  float k2b = k2[(size_t)b * II + tid + 256];
  #pragma unroll
  for (int jj = 0; jj < 16; ++jj) {
    float q2v = q2[(size_t)b * JJ + j0 + jj];
    acc0[jj] = -TEMPF * (q2v + k2a - 2.f * acc0[jj]);
    acc1[jj] = -TEMPF * (q2v + k2b - 2.f * acc1[jj]);
  }
  // log_softmax over i
  #pragma unroll
  for (int jj = 0; jj < 16; ++jj) red[jj][tid] = fmaxf(acc0[jj], acc1[jj]);
  __syncthreads();
  for (int s = 128; s > 0; s >>= 1) {
    if (tid < s) {
      #pragma unroll
      for (int jj = 0; jj < 16; ++jj) red[jj][tid] = fmaxf(red[jj][tid], red[jj][tid + s]);
    }
    __syncthreads();
  }
  float rmax[16];
  #pragma unroll
  for (int jj = 0; jj < 16; ++jj) rmax[jj] = red[jj][0];
  __syncthreads();
  #pragma unroll
  for (int jj = 0; jj < 16; ++jj)
    red[jj][tid] = expf(acc0[jj] - rmax[jj]) + expf(acc1[jj] - rmax[jj]);
  __syncthreads();
  for (int s = 128; s > 0; s >>= 1) {
    if (tid < s) {
      #pragma unroll
      for (int jj = 0; jj < 16; ++jj) red[jj][tid] += red[jj][tid + s];
    }
    __syncthreads();
  }
  float rlse[16];
  #pragma unroll
  for (int jj = 0; jj < 16; ++jj) rlse[jj] = rmax[jj] + logf(red[jj][0]);
  __syncthreads();
  int m0 = tmask[b * II + tid] > 0;
  int m1 = tmask[b * II + tid + 256] > 0;
  #pragma unroll
  for (int jj = 0; jj < 16; ++jj) {
    size_t rowoff = ((size_t)b * JJ + j0 + jj) * II;
    float p0 = prior[rowoff + tid];
    float p1 = prior[rowoff + tid + 256];
    float lp0 = acc0[jj] - rlse[jj] + logf(p0 + 1e-8f);
    float lp1 = acc1[jj] - rlse[jj] + logf(p1 + 1e-8f);
    if (!m0) lp0 = NEGF;
    if (!m1) lp1 = NEGF;
    logp[rowoff + tid] = lp0;
    logp[rowoff + tid + 256] = lp1;
    acc0[jj] = lp0; acc1[jj] = lp1;
  }
  // softmax over masked logp
  #pragma unroll
  for (int jj = 0; jj < 16; ++jj) red[jj][tid] = fmaxf(acc0[jj], acc1[jj]);
  __syncthreads();
  for (int s = 128; s > 0; s >>= 1) {
    if (tid < s) {
      #pragma unroll
      for (int jj = 0; jj < 16; ++jj) red[jj][tid] = fmaxf(red[jj][tid], red[jj][tid + s]);
    }
    __syncthreads();
  }
  #pragma unroll
  for (int jj = 0; jj < 16; ++jj) rmax[jj] = red[jj][0];
  __syncthreads();
  #pragma unroll
  for (int jj = 0; jj < 16; ++jj)
    red[jj][tid] = expf(acc0[jj] - rmax[jj]) + expf(acc1[jj] - rmax[jj]);
  __syncthreads();
  for (int s = 128; s > 0; s >>= 1) {
    if (tid < s) {
      #pragma unroll
      for (int jj = 0; jj < 16; ++jj) red[jj][tid] += red[jj][tid + s];
    }
    __syncthreads();
  }
  #pragma unroll
  for (int jj = 0; jj < 16; ++jj) {
    float inv = 1.f / red[jj][0];
    size_t rowoff = ((size_t)b * JJ + j0 + jj) * II;
    soft[rowoff + tid] = expf(acc0[jj] - rmax[jj]) * inv;
    soft[rowoff + tid + 256] = expf(acc1[jj] - rmax[jj]) * inv;
  }
}

// ---------------- MAS forward: one wave per batch, 8 x-states per lane in registers
__global__ __launch_bounds__(64) void mas_forward(
    const float* __restrict__ soft, const int* __restrict__ tmask,
    const int* __restrict__ mmask, float* __restrict__ V) {
  int b = blockIdx.x;
  int lane = threadIdx.x;
  float v[8];
  int tm[8];
  #pragma unroll
  for (int r = 0; r < 8; ++r) {
    v[r] = NEGF;
    tm[r] = tmask[b * II + lane * 8 + r];
  }
  const float* sb = soft + (size_t)b * JJ * II;
  float* Vb = V + (size_t)b * JJ * II;
  for (int y = 0; y < JJ; ++y) {
    int my = mmask[b * JJ + y] > 0;
    const float4* p = (const float4*)(sb + (size_t)y * II + lane * 8);
    float4 c0 = p[0], c1 = p[1];
    float col[8] = {c0.x, c0.y, c0.z, c0.w, c1.x, c1.y, c1.z, c1.w};
    float prev_last = __shfl_up(v[7], 1);
    if (lane == 0) prev_last = (y == 0) ? 0.f : NEGF;
    float nv[8];
    #pragma unroll
    for (int r = 0; r < 8; ++r) {
      int x = lane * 8 + r;
      float val = (tm[r] && my) ? col[r] : NEGF;
      float vc = (x == y) ? NEGF : v[r];
      float vp = (r == 0) ? prev_last : v[r - 1];
      nv[r] = fmaxf(vp, vc) + val;
    }
    #pragma unroll
    for (int r = 0; r < 8; ++r) v[r] = nv[r];
    float4* vo = (float4*)(Vb + (size_t)y * II + lane * 8);
    vo[0] = make_float4(v[0], v[1], v[2], v[3]);
    vo[1] = make_float4(v[4], v[5], v[6], v[7]);
  }
}

// ---------------- backtrack: 1 thread per batch; records path idx per y + durations
__global__ void mas_backtrack(const float* __restrict__ V, const int* __restrict__ lens,
                              int* __restrict__ pathi, float* __restrict__ dur) {
  int b = blockIdx.x;
  if (threadIdx.x != 0) return;
  int tx = lens[b], ty = lens[BB + b];
  const float* Vb = V + (size_t)b * JJ * II;
  int idx = tx - 1;
  int cnt = 0;
  for (int y = JJ - 1; y >= 0; --y) {
    int active = y < ty;
    if (active) {
      pathi[b * JJ + y] = idx;
      cnt++;
      int move = 0;
      if (idx != 0) {
        if (idx == y) move = 1;
        else if (y > 0) {
          float vc = Vb[(size_t)(y - 1) * II + idx];
          float vp = Vb[(size_t)(y - 1) * II + idx - 1];
          move = (vc < vp) ? 1 : 0;
        }
      }
      if (move) { dur[b * II + idx] = (float)cnt; cnt = 0; idx -= 1; }
    } else {
      pathi[b * JJ + y] = -1;
    }
  }
  dur[b * II + idx] = (float)cnt;
}

// ---------------- expand path indices into full 0/1 mas tensor (overwrites V region)
__global__ __launch_bounds__(64) void mas_expand(const int* __restrict__ pathi,
                                                 float* __restrict__ mas) {
  int row = blockIdx.x;  // b*JJ + y
  int p = pathi[row];
  int lane = threadIdx.x;
  float vals[8];
  #pragma unroll
  for (int r = 0; r < 8; ++r) vals[r] = (lane * 8 + r == p) ? 1.f : 0.f;
  float4* dst = (float4*)(mas + (size_t)row * II + lane * 8);
  dst[0] = make_float4(vals[0], vals[1], vals[2], vals[3]);
  dst[1] = make_float4(vals[4], vals[5], vals[6], vals[7]);
}

// ---------------- CTC: per-row logsumexp over [blank, logp row] with key-mask
__global__ __launch_bounds__(64) void ctc_lse(const float* __restrict__ logp,
                                              const int* __restrict__ lens,
                                              float* __restrict__ lse) {
  int t = blockIdx.x, b = blockIdx.y;
  int lane = threadIdx.x;
  int kl = lens[b];
  const float* row = logp + ((size_t)b * JJ + t) * II;
  float vals[8];
  float mx = (lane == 0) ? BLANKF : NEGF;
  #pragma unroll
  for (int r = 0; r < 8; ++r) {
    int kk = lane * 8 + r;
    float v = (kk + 1 <= kl) ? row[kk] : NEGF;
    vals[r] = v;
    mx = fmaxf(mx, v);
  }
  for (int off = 32; off > 0; off >>= 1) mx = fmaxf(mx, __shfl_xor(mx, off));
  float se = (lane == 0) ? expf(BLANKF - mx) : 0.f;
  #pragma unroll
  for (int r = 0; r < 8; ++r) se += expf(vals[r] - mx);
  for (int off = 32; off > 0; off >>= 1) se += __shfl_xor(se, off);
  if (lane == 0) lse[(size_t)b * JJ + t] = mx + logf(se);
}

// ---------------- CTC forward scan
__global__ __launch_bounds__(1024) void ctc_forward(
    const float* __restrict__ logp, const float* __restrict__ lse,
    const int* __restrict__ lens, float* __restrict__ loss) {
  __shared__ float alpha[1025];
  int b = blockIdx.x;
  int tid = threadIdx.x;
  int kl = lens[b];
  int ql = lens[BB + b];
  int S = 2 * kl + 1;
  alpha[tid] = NEGF;
  if (tid == 0) alpha[1024] = NEGF;
  __syncthreads();
  const float* lpb = logp + (size_t)b * JJ * II;
  const float* lseb = lse + (size_t)b * JJ;
  int odd = tid & 1;
  int kk = (tid + 1) / 2 - 1;  // text index for odd states
  int kvalid = odd && ((tid + 1) / 2 <= kl);
  float vcur = NEGF;
  if (kvalid) vcur = lpb[kk];
  float lcur = lseb[0];
  for (int t = 0; t < JJ; ++t) {
    float vnext = NEGF, lnext = 0.f;
    if (t + 1 < JJ) {
      if (kvalid) vnext = lpb[(size_t)(t + 1) * II + kk];
      lnext = lseb[t + 1];
    }
    int s = tid;
    float e1 = (odd ? vcur : BLANKF) - lcur;
    float a1 = alpha[s];
    float a2 = (s >= 1) ? alpha[s - 1] : NEGF;
    float a3 = (s >= 2 && odd) ? alpha[s - 2] : NEGF;
    float prev = lae(lae(a1, a2), a3);
    if (t == 0) prev = (s <= 1) ? 0.f : NEGF;
    float nv = (s < S) ? prev + e1 : NEGF;
    if (t >= ql) nv = a1;
    float nv2 = 0.f;
    if (tid == 0) {
      float e2 = BLANKF - lcur;
      float b1 = alpha[1024], b2 = alpha[1023];
      float pv = lae(b1, b2);
      if (t == 0) pv = NEGF;
      nv2 = (1024 < S) ? pv + e2 : NEGF;
      if (t >= ql) nv2 = b1;
    }
    __syncthreads();
    alpha[s] = nv;
    if (tid == 0) alpha[1024] = nv2;
    __syncthreads();
    vcur = vnext; lcur = lnext;
  }
  if (tid == 0) {
    float ll = lae(alpha[2 * kl], alpha[2 * kl - 1]);
    atomicAdd(loss, -ll / (float)kl / (float)BB);
  }
}

extern "C" void kernel_launch(void* const* d_in, const int* in_sizes, int n_in,
                              void* d_out, int out_size, void* d_ws, size_t ws_size,
                              hipStream_t stream) {
  const float* text = (const float*)d_in[0];
  const float* mel  = (const float*)d_in[1];
  const int* tmask  = (const int*)d_in[2];
  const int* mmask  = (const int*)d_in[3];
  const float* prior = (const float*)d_in[4];
  const float* kw1 = (const float*)d_in[5];
  const float* kb1 = (const float*)d_in[6];
  const float* kw2 = (const float*)d_in[7];
  const float* kb2 = (const float*)d_in[8];
  const float* qw1 = (const float*)d_in[9];
  const float* qb1 = (const float*)d_in[10];
  const float* qw2 = (const float*)d_in[11];
  const float* qb2 = (const float*)d_in[12];
  const float* qw3 = (const float*)d_in[13];
  const float* qb3 = (const float*)d_in[14];

  float* ws = (float*)d_ws;
  float* big   = ws;              // kc (8,388,608 f) then qc (5,242,880 f)
  float* slotY = ws + 8388608;    // textT (4,194,304 f) then q1 (2,621,440 f)
  float* slotZ = ws + 12582912;   // melT (2,621,440 f) then q (2,621,440 f)
  float* kbuf  = ws + 15204352;   // k (655,360 f)
  float* k2    = ws + 15859712;   // 8192
  float* q2    = ws + 15867904;   // 32768
  float* lse   = ws + 15900672;   // 32768
  int*   lens  = (int*)(ws + 15933440);  // 32
  int*   pathi = (int*)(ws + 15933472);  // 32768

  float* out  = (float*)d_out;
  float* dur  = out;                 // 8192
  float* soft = out + 8192;          // 16,777,216
  float* logp = out + 16785408;      // 16,777,216
  float* mas  = out + 33562624;      // 16,777,216
  float* loss = out + 50339840;      // 1
  float* V = mas;  // V table reuses the mas output region (rewritten by mas_expand)

  hipMemsetAsync(dur, 0, 8192 * sizeof(float), stream);
  hipMemsetAsync(loss, 0, sizeof(float), stream);

  compute_lens<<<BB, 256, 0, stream>>>(tmask, mmask, lens);

  dim3 t8(32, 8);
  transpose_bc<<<dim3(II / 32, CT / 32, BB), t8, 0, stream>>>(text, slotY, II, CT);
  conv3_relu<<<dim3(II / 128, 1024 / 64, BB), 256, 0, stream>>>(slotY, kw1, kb1, big, CT, 1024, II);
  pw_gemm<<<dim3(II / 64, BB), 256, 0, stream>>>(big, kw2, kb2, kbuf, k2, 1024, II, 0);

  transpose_bc<<<dim3(JJ / 32, 3, BB), t8, 0, stream>>>(mel, slotZ, JJ, CM);
  conv3_relu<<<dim3(JJ / 128, 3, BB), 256, 0, stream>>>(slotZ, qw1, qb1, big, CM, 160, JJ);
  pw_gemm<<<dim3(JJ / 64, BB), 256, 0, stream>>>(big, qw2, qb2, slotY, nullptr, 160, JJ, 1);
  pw_gemm<<<dim3(JJ / 64, BB), 256, 0, stream>>>(slotY, qw3, qb3, slotZ, q2, AC, JJ, 0);

  attn_logits<<<dim3(JJ / 16, BB), 256, 0, stream>>>(slotZ, kbuf, q2, k2, prior, tmask, soft, logp);

  mas_forward<<<BB, 64, 0, stream>>>(soft, tmask, mmask, V);
  mas_backtrack<<<BB, 64, 0, stream>>>(V, lens, pathi, dur);
  mas_expand<<<BB * JJ, 64, 0, stream>>>(pathi, mas);

  ctc_lse<<<dim3(JJ, BB), 64, 0, stream>>>(logp, lens, lse);
  ctc_forward<<<BB, 1024, 0, stream>>>(logp, lse, lens, loss);
}

// Round 4
// 3636.554 us; speedup vs baseline: 1.8340x; 1.8340x over previous
//
#include <hip/hip_runtime.h>
#include <hip/hip_bf16.h>
#include <math.h>

#define BB 16
#define II 512
#define JJ 2048
#define CT 512
#define CM 80
#define AC 80

#define NEGF (-1000000000.0f)
#define TEMPF 0.0005f
#define BLANKF (-1.0f)
#define LOG2E 1.44269504088896340736f
#define LN2 0.693147180559945309f

__device__ __forceinline__ float lae(float a, float b) {
  float m = fmaxf(a, b);
  return m + log1pf(expf(-fabsf(a - b)));
}

// ---------------- lens: key_lens[b] = sum(text_mask), query_lens[b] = sum(mel_mask)
__global__ void compute_lens(const int* __restrict__ tmask, const int* __restrict__ mmask,
                             int* __restrict__ lens) {
  __shared__ int sred[256];
  int b = blockIdx.x, tid = threadIdx.x;
  int s = 0;
  for (int i = tid; i < II; i += 256) s += (tmask[b * II + i] > 0);
  sred[tid] = s; __syncthreads();
  for (int st = 128; st > 0; st >>= 1) { if (tid < st) sred[tid] += sred[tid + st]; __syncthreads(); }
  if (tid == 0) lens[b] = sred[0];
  __syncthreads();
  s = 0;
  for (int i = tid; i < JJ; i += 256) s += (mmask[b * JJ + i] > 0);
  sred[tid] = s; __syncthreads();
  for (int st = 128; st > 0; st >>= 1) { if (tid < st) sred[tid] += sred[tid + st]; __syncthreads(); }
  if (tid == 0) lens[BB + b] = sred[0];
}

// ---------------- transpose (B, L, C) -> (B, C, L)
__global__ void transpose_bc(const float* __restrict__ x, float* __restrict__ y, int L, int C) {
  __shared__ float tile[32][33];
  int b = blockIdx.z;
  int l0 = blockIdx.x * 32, c0 = blockIdx.y * 32;
  int tx = threadIdx.x, ty = threadIdx.y;
  for (int r = ty; r < 32; r += 8) {
    int l = l0 + r, c = c0 + tx;
    tile[r][tx] = (l < L && c < C) ? x[((size_t)b * L + l) * C + c] : 0.f;
  }
  __syncthreads();
  for (int r = ty; r < 32; r += 8) {
    int c = c0 + r, l = l0 + tx;
    if (c < C && l < L) y[((size_t)b * C + c) * L + l] = tile[tx][r];
  }
}

// ---------------- conv k=3 SAME + relu
__global__ __launch_bounds__(256) void conv3_relu(
    const float* __restrict__ X, const float* __restrict__ W,
    const float* __restrict__ bias, float* __restrict__ Y,
    int Cin, int O, int L) {
  __shared__ float xs[16][132];
  __shared__ float wsm[64][49];
  int b = blockIdx.z;
  int l0 = blockIdx.x * 128;
  int o0 = blockIdx.y * 64;
  int tid = threadIdx.x;
  int tx = tid & 15, ty = tid >> 4;
  float acc[4][8] = {};
  const float* Xb = X + (size_t)b * Cin * L;
  for (int c0 = 0; c0 < Cin; c0 += 16) {
    for (int idx = tid; idx < 16 * 130; idx += 256) {
      int cc = idx / 130, ll = idx % 130;
      int l = l0 + ll - 1;
      xs[cc][ll] = (l >= 0 && l < L) ? Xb[(size_t)(c0 + cc) * L + l] : 0.f;
    }
    for (int idx = tid; idx < 64 * 48; idx += 256) {
      int oo = idx / 48, kx = idx % 48;
      int o = o0 + oo;
      wsm[oo][kx] = (o < O) ? W[((size_t)o * Cin + (c0 + (kx / 3))) * 3 + (kx % 3)] : 0.f;
    }
    __syncthreads();
    #pragma unroll 4
    for (int cc = 0; cc < 16; ++cc) {
      float xr[10];
      #pragma unroll
      for (int u = 0; u < 10; ++u) xr[u] = xs[cc][tx * 8 + u];
      #pragma unroll
      for (int a = 0; a < 4; ++a) {
        float w0 = wsm[ty * 4 + a][cc * 3 + 0];
        float w1 = wsm[ty * 4 + a][cc * 3 + 1];
        float w2 = wsm[ty * 4 + a][cc * 3 + 2];
        #pragma unroll
        for (int ii = 0; ii < 8; ++ii)
          acc[a][ii] += w0 * xr[ii] + w1 * xr[ii + 1] + w2 * xr[ii + 2];
      }
    }
    __syncthreads();
  }
  #pragma unroll
  for (int a = 0; a < 4; ++a) {
    int o = o0 + ty * 4 + a;
    if (o < O) {
      float bv = bias[o];
      #pragma unroll
      for (int ii = 0; ii < 8; ++ii) {
        int l = l0 + tx * 8 + ii;
        Y[((size_t)b * O + o) * L + l] = fmaxf(acc[a][ii] + bv, 0.f);
      }
    }
  }
}

// ---------------- pointwise GEMM (Aout = 80)
__global__ __launch_bounds__(256) void pw_gemm(
    const float* __restrict__ X, const float* __restrict__ W,
    const float* __restrict__ bias, float* __restrict__ Y,
    float* __restrict__ sq, int K, int L, int relu) {
  __shared__ float xsm[16][65];
  __shared__ float wsm[80][17];
  __shared__ float red[4][64];
  int b = blockIdx.y;
  int l0 = blockIdx.x * 64;
  int tid = threadIdx.x;
  int tx = tid & 63, ty = tid >> 6;
  float acc[20] = {};
  const float* Xb = X + (size_t)b * K * L;
  for (int k0 = 0; k0 < K; k0 += 16) {
    for (int idx = tid; idx < 16 * 64; idx += 256) {
      int kk = idx >> 6, ll = idx & 63;
      xsm[kk][ll] = Xb[(size_t)(k0 + kk) * L + l0 + ll];
    }
    for (int idx = tid; idx < 80 * 16; idx += 256) {
      int aa = idx >> 4, kk = idx & 15;
      wsm[aa][kk] = W[(size_t)aa * K + k0 + kk];
    }
    __syncthreads();
    #pragma unroll 4
    for (int kk = 0; kk < 16; ++kk) {
      float xv = xsm[kk][tx];
      #pragma unroll
      for (int aa = 0; aa < 20; ++aa) acc[aa] += wsm[ty + 4 * aa][kk] * xv;
    }
    __syncthreads();
  }
  float s2 = 0.f;
  #pragma unroll
  for (int aa = 0; aa < 20; ++aa) {
    int a = ty + 4 * aa;
    float v = acc[aa] + bias[a];
    if (relu) v = fmaxf(v, 0.f);
    Y[((size_t)b * 80 + a) * L + l0 + tx] = v;
    s2 += v * v;
  }
  if (sq) {
    red[ty][tx] = s2;
    __syncthreads();
    if (ty == 0) sq[(size_t)b * L + l0 + tx] = red[0][tx] + red[1][tx] + red[2][tx] + red[3][tx];
  }
}

// ---------------- block reduction over 256 threads of 16 per-row values
template<bool IS_MAX>
__device__ __forceinline__ void reduce16(const float vals[16], float out[16],
                                         float (*red)[257], int tid) {
  #pragma unroll
  for (int jj = 0; jj < 16; ++jj) red[jj][tid] = vals[jj];
  __syncthreads();
  int myjj = tid >> 4, c = tid & 15;
  float r = red[myjj][c];
  #pragma unroll
  for (int k = 1; k < 16; ++k) {
    float x = red[myjj][c + 16 * k];
    r = IS_MAX ? fmaxf(r, x) : (r + x);
  }
  #pragma unroll
  for (int m = 8; m >= 1; m >>= 1) {
    float x = __shfl_xor(r, m);
    r = IS_MAX ? fmaxf(r, x) : (r + x);
  }
  if (c == 0) red[myjj][256] = r;
  __syncthreads();
  #pragma unroll
  for (int jj = 0; jj < 16; ++jj) out[jj] = red[jj][256];
}

// ---------------- attention: logits + log_softmax + prior + mask -> logp; softmax -> soft
__global__ __launch_bounds__(256) void attn_logits(
    const float* __restrict__ q, const float* __restrict__ k,
    const float* __restrict__ q2, const float* __restrict__ k2,
    const float* __restrict__ prior, const int* __restrict__ tmask,
    float* __restrict__ soft, float* __restrict__ logp) {
  __shared__ float kS[16][II];
  __shared__ float qS[16][16];
  __shared__ float red[16][257];
  int b = blockIdx.y;
  int j0 = blockIdx.x * 16;
  int tid = threadIdx.x;
  float acc0[16] = {}, acc1[16] = {};
  for (int c0 = 0; c0 < AC; c0 += 16) {
    for (int idx = tid; idx < 16 * II; idx += 256) {
      int cc = idx >> 9, ii = idx & 511;
      kS[cc][ii] = k[((size_t)b * AC + c0 + cc) * II + ii];
    }
    {
      int cc = tid >> 4, jl = tid & 15;
      qS[cc][jl] = q[((size_t)b * AC + c0 + cc) * JJ + j0 + jl];
    }
    __syncthreads();
    #pragma unroll 4
    for (int cc = 0; cc < 16; ++cc) {
      float k0v = kS[cc][tid], k1v = kS[cc][tid + 256];
      #pragma unroll
      for (int jj = 0; jj < 16; ++jj) {
        float qv = qS[cc][jj];
        acc0[jj] += qv * k0v;
        acc1[jj] += qv * k1v;
      }
    }
    __syncthreads();
  }
  float k2a = k2[(size_t)b * II + tid];
  float k2b = k2[(size_t)b * II + tid + 256];
  #pragma unroll
  for (int jj = 0; jj < 16; ++jj) {
    float q2v = q2[(size_t)b * JJ + j0 + jj];
    acc0[jj] = -TEMPF * (q2v + k2a - 2.f * acc0[jj]);
    acc1[jj] = -TEMPF * (q2v + k2b - 2.f * acc1[jj]);
  }
  float vals[16], rmax[16], rsum[16];
  // log_softmax over i
  #pragma unroll
  for (int jj = 0; jj < 16; ++jj) vals[jj] = fmaxf(acc0[jj], acc1[jj]);
  reduce16<true>(vals, rmax, red, tid);
  #pragma unroll
  for (int jj = 0; jj < 16; ++jj)
    vals[jj] = expf(acc0[jj] - rmax[jj]) + expf(acc1[jj] - rmax[jj]);
  reduce16<false>(vals, rsum, red, tid);
  int m0 = tmask[b * II + tid] > 0;
  int m1 = tmask[b * II + tid + 256] > 0;
  #pragma unroll
  for (int jj = 0; jj < 16; ++jj) {
    float rlse = rmax[jj] + logf(rsum[jj]);
    size_t rowoff = ((size_t)b * JJ + j0 + jj) * II;
    float p0 = prior[rowoff + tid];
    float p1 = prior[rowoff + tid + 256];
    float lp0 = acc0[jj] - rlse + logf(p0 + 1e-8f);
    float lp1 = acc1[jj] - rlse + logf(p1 + 1e-8f);
    if (!m0) lp0 = NEGF;
    if (!m1) lp1 = NEGF;
    logp[rowoff + tid] = lp0;
    logp[rowoff + tid + 256] = lp1;
    acc0[jj] = lp0; acc1[jj] = lp1;
  }
  // softmax over masked logp
  #pragma unroll
  for (int jj = 0; jj < 16; ++jj) vals[jj] = fmaxf(acc0[jj], acc1[jj]);
  reduce16<true>(vals, rmax, red, tid);
  float e0[16], e1[16];
  #pragma unroll
  for (int jj = 0; jj < 16; ++jj) {
    e0[jj] = expf(acc0[jj] - rmax[jj]);
    e1[jj] = expf(acc1[jj] - rmax[jj]);
    vals[jj] = e0[jj] + e1[jj];
  }
  reduce16<false>(vals, rsum, red, tid);
  #pragma unroll
  for (int jj = 0; jj < 16; ++jj) {
    float inv = 1.f / rsum[jj];
    size_t rowoff = ((size_t)b * JJ + j0 + jj) * II;
    soft[rowoff + tid] = e0[jj] * inv;
    soft[rowoff + tid + 256] = e1[jj] * inv;
  }
}

// ---------------- MAS fused: forward DP (move bits to ws) + in-kernel backtrack
__global__ __launch_bounds__(64) void mas_fused(
    const float* __restrict__ soft, const int* __restrict__ tmask,
    const int* __restrict__ mmask, const int* __restrict__ lens,
    unsigned char* __restrict__ moves, int* __restrict__ pathi,
    float* __restrict__ dur) {
  int b = blockIdx.x;
  int lane = threadIdx.x;
  float v[8];
  int tm[8];
  #pragma unroll
  for (int r = 0; r < 8; ++r) {
    v[r] = NEGF;
    tm[r] = tmask[b * II + lane * 8 + r];
  }
  const float* sb = soft + (size_t)b * JJ * II + lane * 8;
  unsigned char* mrow = moves + (size_t)b * JJ * 64;
  float4 c0 = *(const float4*)(sb);
  float4 c1 = *(const float4*)(sb + 4);
  int my = mmask[b * JJ] > 0;
  for (int y = 0; y < JJ; ++y) {
    float4 n0 = c0, n1 = c1;
    int nmy = my;
    if (y + 1 < JJ) {
      n0 = *(const float4*)(sb + (size_t)(y + 1) * II);
      n1 = *(const float4*)(sb + (size_t)(y + 1) * II + 4);
      nmy = mmask[b * JJ + y + 1] > 0;
    }
    float col[8] = {c0.x, c0.y, c0.z, c0.w, c1.x, c1.y, c1.z, c1.w};
    float vl = __shfl_up(v[7], 1);  // raw left neighbor boundary (lane0: unused for bits)
    // move bits from OLD v (= V[y-1]); bit for x=0 never used by backtrack
    unsigned int mb = 0;
    #pragma unroll
    for (int r = 0; r < 8; ++r) {
      int x = lane * 8 + r;
      float left = r ? v[r - 1] : vl;
      if ((x == y) || (v[r] < left)) mb |= (1u << r);
    }
    mrow[(size_t)y * 64 + lane] = (unsigned char)mb;
    float prev_last = (lane == 0) ? ((y == 0) ? 0.f : NEGF) : vl;
    float nv[8];
    #pragma unroll
    for (int r = 0; r < 8; ++r) {
      int x = lane * 8 + r;
      float val = (tm[r] && my) ? col[r] : NEGF;
      float vc = (x == y) ? NEGF : v[r];
      float vp = (r == 0) ? prev_last : v[r - 1];
      nv[r] = fmaxf(vp, vc) + val;
    }
    #pragma unroll
    for (int r = 0; r < 8; ++r) v[r] = nv[r];
    c0 = n0; c1 = n1; my = nmy;
  }
  __syncthreads();
  if (lane == 0) {
    int tx = lens[b], ty = lens[BB + b];
    int idx = tx - 1;
    int cnt = 0;
    for (int y = JJ - 1; y >= 0; --y) {
      if (y < ty) {
        pathi[b * JJ + y] = idx;
        cnt++;
        int move = 0;
        if (idx != 0) move = (mrow[(size_t)y * 64 + (idx >> 3)] >> (idx & 7)) & 1;
        if (move) { dur[b * II + idx] = (float)cnt; cnt = 0; idx -= 1; }
      } else {
        pathi[b * JJ + y] = -1;
      }
    }
    dur[b * II + idx] = (float)cnt;
  }
}

// ---------------- expand path indices into full 0/1 mas tensor
__global__ __launch_bounds__(64) void mas_expand(const int* __restrict__ pathi,
                                                 float* __restrict__ mas) {
  int row = blockIdx.x;  // b*JJ + y
  int p = pathi[row];
  int lane = threadIdx.x;
  float vals[8];
  #pragma unroll
  for (int r = 0; r < 8; ++r) vals[r] = (lane * 8 + r == p) ? 1.f : 0.f;
  float4* dst = (float4*)(mas + (size_t)row * II + lane * 8);
  dst[0] = make_float4(vals[0], vals[1], vals[2], vals[3]);
  dst[1] = make_float4(vals[4], vals[5], vals[6], vals[7]);
}

// ---------------- CTC: per-row logsumexp over [blank, logp row] with key-mask
__global__ __launch_bounds__(64) void ctc_lse(const float* __restrict__ logp,
                                              const int* __restrict__ lens,
                                              float* __restrict__ lse) {
  int t = blockIdx.x, b = blockIdx.y;
  int lane = threadIdx.x;
  int kl = lens[b];
  const float* row = logp + ((size_t)b * JJ + t) * II;
  float vals[8];
  float mx = (lane == 0) ? BLANKF : NEGF;
  #pragma unroll
  for (int r = 0; r < 8; ++r) {
    int kk = lane * 8 + r;
    float v = (kk + 1 <= kl) ? row[kk] : NEGF;
    vals[r] = v;
    mx = fmaxf(mx, v);
  }
  for (int off = 32; off > 0; off >>= 1) mx = fmaxf(mx, __shfl_xor(mx, off));
  float se = (lane == 0) ? expf(BLANKF - mx) : 0.f;
  #pragma unroll
  for (int r = 0; r < 8; ++r) se += expf(vals[r] - mx);
  for (int off = 32; off > 0; off >>= 1) se += __shfl_xor(se, off);
  if (lane == 0) lse[(size_t)b * JJ + t] = mx + logf(se);
}

// ---------------- CTC forward: 4 waves, 4 states/thread in registers, log2 domain,
// one barrier/step, boundary via double-buffered LDS slot
__global__ __launch_bounds__(256) void ctc_forward_block(
    const float* __restrict__ logp, const float* __restrict__ lse,
    const int* __restrict__ lens, float* __restrict__ loss) {
  __shared__ float bound[2][4];
  __shared__ float alpha_s[1025];
  int b = blockIdx.x;
  int tid = threadIdx.x;
  int w = tid >> 6, lane = tid & 63;
  int kl = lens[b], ql = lens[BB + b];
  int S = 2 * kl + 1;
  const float* lpb = logp + (size_t)b * JJ * II + tid * 2;
  const float* lseb = lse + (size_t)b * JJ;
  bool valid[4];
  #pragma unroll
  for (int r = 0; r < 4; ++r) valid[r] = (tid * 4 + r) < S;
  bool vtop = (tid == 255) && (1024 < S);
  float a[4];
  float atop = NEGF;
  // t = 0 (prev = 0 for s<=1 else NEG)
  float2 c = *(const float2*)lpb;
  float clse = lseb[0];
  {
    float eb = (BLANKF - clse) * LOG2E;
    float p01 = (tid == 0) ? 0.f : NEGF;
    a[0] = valid[0] ? p01 + eb : NEGF;
    a[1] = valid[1] ? p01 + (c.x - clse) * LOG2E : NEGF;
    a[2] = valid[2] ? NEGF + eb : NEGF;
    a[3] = valid[3] ? NEGF + (c.y - clse) * LOG2E : NEGF;
    if (vtop) atop = NEGF + eb;
  }
  float2 n = c;
  float nlse = clse;
  if (ql > 1) { n = *(const float2*)(lpb + II); nlse = lseb[1]; }
  for (int t = 1; t < ql; ++t) {
    if (lane == 63) bound[t & 1][w] = a[3];
    float2 cc = n;
    float cl = nlse;
    if (t + 1 < ql) {
      n = *(const float2*)(lpb + (size_t)(t + 1) * II);
      nlse = lseb[t + 1];
    }
    __syncthreads();
    float shv = __shfl_up(a[3], 1);
    if (lane == 0) shv = (w == 0) ? NEGF : bound[t & 1][w - 1];
    float eb = (BLANKF - cl) * LOG2E;
    float na0, na1, na2, na3;
    {  // r=0 even: prev = lse2(a[0], shv)
      float a1 = a[0], a2 = shv;
      float m = fmaxf(a1, a2);
      float prev = m + log2f(1.f + exp2f(-fabsf(a1 - a2)));
      na0 = valid[0] ? prev + eb : NEGF;
    }
    {  // r=1 odd: prev = lse3(a[1], a[0], shv)  (tid==0: shv==NEG covers skip_ok)
      float a1 = a[1], a2 = a[0], a3 = shv;
      float m = fmaxf(fmaxf(a1, a2), a3);
      float prev = m + log2f(exp2f(a1 - m) + exp2f(a2 - m) + exp2f(a3 - m));
      na1 = valid[1] ? prev + (cc.x - cl) * LOG2E : NEGF;
    }
    {  // r=2 even
      float a1 = a[2], a2 = a[1];
      float m = fmaxf(a1, a2);
      float prev = m + log2f(1.f + exp2f(-fabsf(a1 - a2)));
      na2 = valid[2] ? prev + eb : NEGF;
    }
    {  // r=3 odd
      float a1 = a[3], a2 = a[2], a3 = a[1];
      float m = fmaxf(fmaxf(a1, a2), a3);
      float prev = m + log2f(exp2f(a1 - m) + exp2f(a2 - m) + exp2f(a3 - m));
      na3 = valid[3] ? prev + (cc.y - cl) * LOG2E : NEGF;
    }
    if (vtop) {  // state 1024 (even): lse2(atop, a[3]) + eb
      float a1 = atop, a2 = a[3];
      float m = fmaxf(a1, a2);
      atop = m + log2f(1.f + exp2f(-fabsf(a1 - a2))) + eb;
    }
    a[0] = na0; a[1] = na1; a[2] = na2; a[3] = na3;
  }
  alpha_s[tid * 4 + 0] = a[0];
  alpha_s[tid * 4 + 1] = a[1];
  alpha_s[tid * 4 + 2] = a[2];
  alpha_s[tid * 4 + 3] = a[3];
  if (tid == 255) alpha_s[1024] = atop;
  __syncthreads();
  if (tid == 0) {
    float e1 = alpha_s[2 * kl] * LN2;
    float e2 = alpha_s[2 * kl - 1] * LN2;
    float ll = lae(e1, e2);
    atomicAdd(loss, -ll / (float)kl / (float)BB);
  }
}

extern "C" void kernel_launch(void* const* d_in, const int* in_sizes, int n_in,
                              void* d_out, int out_size, void* d_ws, size_t ws_size,
                              hipStream_t stream) {
  const float* text = (const float*)d_in[0];
  const float* mel  = (const float*)d_in[1];
  const int* tmask  = (const int*)d_in[2];
  const int* mmask  = (const int*)d_in[3];
  const float* prior = (const float*)d_in[4];
  const float* kw1 = (const float*)d_in[5];
  const float* kb1 = (const float*)d_in[6];
  const float* kw2 = (const float*)d_in[7];
  const float* kb2 = (const float*)d_in[8];
  const float* qw1 = (const float*)d_in[9];
  const float* qb1 = (const float*)d_in[10];
  const float* qw2 = (const float*)d_in[11];
  const float* qb2 = (const float*)d_in[12];
  const float* qw3 = (const float*)d_in[13];
  const float* qb3 = (const float*)d_in[14];

  float* ws = (float*)d_ws;
  float* big   = ws;              // conv outputs; later reused as move-bit buffer
  float* slotY = ws + 8388608;
  float* slotZ = ws + 12582912;
  float* kbuf  = ws + 15204352;
  float* k2    = ws + 15859712;
  float* q2    = ws + 15867904;
  float* lse   = ws + 15900672;
  int*   lens  = (int*)(ws + 15933440);
  int*   pathi = (int*)(ws + 15933472);
  unsigned char* moves = (unsigned char*)big;  // 16*2048*64 B = 2 MB, conv data dead by then

  float* out  = (float*)d_out;
  float* dur  = out;                 // 8192
  float* soft = out + 8192;          // 16,777,216
  float* logp = out + 16785408;      // 16,777,216
  float* mas  = out + 33562624;      // 16,777,216
  float* loss = out + 50339840;      // 1

  hipMemsetAsync(dur, 0, 8192 * sizeof(float), stream);
  hipMemsetAsync(loss, 0, sizeof(float), stream);

  compute_lens<<<BB, 256, 0, stream>>>(tmask, mmask, lens);

  dim3 t8(32, 8);
  transpose_bc<<<dim3(II / 32, CT / 32, BB), t8, 0, stream>>>(text, slotY, II, CT);
  conv3_relu<<<dim3(II / 128, 1024 / 64, BB), 256, 0, stream>>>(slotY, kw1, kb1, big, CT, 1024, II);
  pw_gemm<<<dim3(II / 64, BB), 256, 0, stream>>>(big, kw2, kb2, kbuf, k2, 1024, II, 0);

  transpose_bc<<<dim3(JJ / 32, 3, BB), t8, 0, stream>>>(mel, slotZ, JJ, CM);
  conv3_relu<<<dim3(JJ / 128, 3, BB), 256, 0, stream>>>(slotZ, qw1, qb1, big, CM, 160, JJ);
  pw_gemm<<<dim3(JJ / 64, BB), 256, 0, stream>>>(big, qw2, qb2, slotY, nullptr, 160, JJ, 1);
  pw_gemm<<<dim3(JJ / 64, BB), 256, 0, stream>>>(slotY, qw3, qb3, slotZ, q2, AC, JJ, 0);

  attn_logits<<<dim3(JJ / 16, BB), 256, 0, stream>>>(slotZ, kbuf, q2, k2, prior, tmask, soft, logp);

  mas_fused<<<BB, 64, 0, stream>>>(soft, tmask, mmask, lens, moves, pathi, dur);
  mas_expand<<<BB * JJ, 64, 0, stream>>>(pathi, mas);

  ctc_lse<<<dim3(JJ, BB), 64, 0, stream>>>(logp, lens, lse);
  ctc_forward_block<<<BB, 256, 0, stream>>>(logp, lse, lens, loss);
}